// Round 13
// baseline (133.005 us; speedup 1.0000x reference)
//
#include <hip/hip_runtime.h>

// Problem constants
#define NSPLIT  100
#define MTREE   20
#define MAXLEAF 64
#define EMB     32
#define NTREES  2000
#define BATCH   4096
#define OUTW    (NSPLIT*EMB)             // 3200
#define TAB_F4  (NSPLIT*MTREE*MAXLEAF*8) // 1,024,000 float4 in f32 table
#define SPLIT_B 81920                    // bf16 table bytes per split
#define PASS_B  40960                    // bf16 bytes per 10-tree pass

#define THREADS 1024
#define CHUNKS  8                        // batch-chunks per split
#define BPC     (BATCH/CHUNKS)           // 512 batches/block, 2 per 4-lane group
#define NBLK    (NSPLIT*CHUNKS)          // 800

// v13 = v12 with staging traffic cut 4x and barriers cut 2x.
// Evidence: wall time tracks staging traffic (262 MB -> ~40us for BOTH v7 and
// v12 despite different structures; 524 MB -> 50us for v10), while LDS port
// and VALU sit at ~30%. So: 800 blocks x 512 batches -> 65 MB staging.
//  - 2 batches per 4-lane group, SEQUENTIAL (leaf regs retire between
//    batches; peak live ~58 < 64 cap from __launch_bounds__(1024,2), the
//    v7-proven spill-free tier).
//  - Double-buffered 40 KiB passes (80 KiB static LDS, 2 blocks/CU):
//    STAGE0; bar; [STAGE1 dma || gather p0 A,B]; bar; gather p1 A,B.
//    Pass-1 DMA hides under pass-0's ~7.7K cycles of ds_reads.
//  - OccupancyPercent dropped as a signal (gfx94x formula fallback; v11
//    reported 17% with zero LDS).
__device__ __forceinline__ unsigned int pk_bf16(float a, float b) {
    unsigned int r;
    asm("v_cvt_pk_bf16_f32 %0, %1, %2" : "=v"(r) : "v"(a), "v"(b));
    return r;
}

__device__ __forceinline__ void stage_dma(const void* gsrc, void* lbase) {
    __builtin_amdgcn_global_load_lds(
        (const __attribute__((address_space(1))) void*)gsrc,
        (__attribute__((address_space(3))) void*)lbase, 16, 0, 0);
}

// ---- kernel 1: f32 table -> bf16 table in d_ws (row-major preserved) ----
__global__ __launch_bounds__(256) void cvt_tab(
    const float4* __restrict__ src, uint2* __restrict__ dst)
{
    const int i0 = blockIdx.x * 1024 + threadIdx.x;
#pragma unroll
    for (int k = 0; k < 4; ++k) {
        const int i = i0 + k * 256;          // 1000 blocks x 1024 = exact
        const float4 v = src[i];
        dst[i] = make_uint2(pk_bf16(v.x, v.y), pk_bf16(v.z, v.w));
    }
}

// ---- kernel 2: LDS gather, double-buffered DMA-staged bf16 passes ----
__global__ __launch_bounds__(THREADS, 2) void leaf2emb_v13(
    const int* __restrict__ leaves,     // [BATCH, NTREES]
    const char* __restrict__ tab,       // bf16 table in d_ws, row = 64 B
    float* __restrict__ out)            // [BATCH, OUTW]
{
    __shared__ char tl[2][PASS_B];      // 2 x 40 KiB

    // XCD-chunked swizzle: 800 = 8 x 100 -> XCD x owns 12.5 consecutive
    // splits; its ~1 MB bf16 slice stays L2-resident for DMA staging.
    const int bid = blockIdx.x;
    const int wkr = (bid & 7) * (NBLK / 8) + (bid >> 3);
    const int s     = wkr >> 3;
    const int chunk = wkr & 7;

    const int tid  = threadIdx.x;
    const int l    = tid & 3;           // lane-in-group: dims [8l, 8l+8)
    const int g    = tid >> 2;          // group id (256 groups, 2 batches each)
    const int w    = tid >> 6;          // wave id (uniform)
    const int lane = tid & 63;

    const char* gtab = tab + (size_t)s * SPLIT_B;

    // 40 KiB = 40 x 1KB DMA chunks over 16 waves: waves 0..7 do 3, 8..15 do 2.
#define STAGE(P, NB) { \
        const char* gs_ = gtab + (P) * PASS_B + w * 1024 + lane * 16; \
        char* lb_ = tl[NB] + w * 1024; \
        stage_dma(gs_,          lb_); \
        stage_dma(gs_ + 16384,  lb_ + 16384); \
        if (w < 8) stage_dma(gs_ + 32768, lb_ + 32768); \
    }

    const int bA = chunk * BPC + g;
    const int bB = bA + 256;
    const int* lvA = leaves + (size_t)bA * NTREES + s * MTREE;
    const int* lvB = leaves + (size_t)bB * NTREES + s * MTREE;

#define RD(TB, T, LEAF) (*(const uint4*)((TB) + (T)*4096 + ((LEAF) << 6)))
#define UNACC(P0, P1, V) { \
    P0.x += __uint_as_float((V).x << 16); P0.y += __uint_as_float((V).x & 0xffff0000u); \
    P0.z += __uint_as_float((V).y << 16); P0.w += __uint_as_float((V).y & 0xffff0000u); \
    P1.x += __uint_as_float((V).z << 16); P1.y += __uint_as_float((V).z & 0xffff0000u); \
    P1.z += __uint_as_float((V).w << 16); P1.w += __uint_as_float((V).w & 0xffff0000u); }

    // 10 trees from a staged pass: 4+4+2 reads in flight (<=4 uint4 live).
#define GATHER10(TB, P0, P1, LQ0, LQ1, LP) { \
        uint4 v0 = RD(TB, 0, (LQ0).x), v1 = RD(TB, 1, (LQ0).y), \
              v2 = RD(TB, 2, (LQ0).z), v3 = RD(TB, 3, (LQ0).w); \
        UNACC(P0, P1, v0) UNACC(P0, P1, v1) UNACC(P0, P1, v2) UNACC(P0, P1, v3) \
        v0 = RD(TB, 4, (LQ1).x); v1 = RD(TB, 5, (LQ1).y); \
        v2 = RD(TB, 6, (LQ1).z); v3 = RD(TB, 7, (LQ1).w); \
        UNACC(P0, P1, v0) UNACC(P0, P1, v1) UNACC(P0, P1, v2) UNACC(P0, P1, v3) \
        v0 = RD(TB, 8, (LP).x);  v1 = RD(TB, 9, (LP).y); \
        UNACC(P0, P1, v0) UNACC(P0, P1, v1) }

    // ---- prologue: stage pass 0 + pass-0 leaves for both batches ----
    STAGE(0, 0)
    int4 LA0 = *(const int4*)(lvA);     int4 LB0 = *(const int4*)(lvB);
    int4 LA1 = *(const int4*)(lvA + 4); int4 LB1 = *(const int4*)(lvB + 4);
    int2 LAh = *(const int2*)(lvA + 8); int2 LBh = *(const int2*)(lvB + 8);

    float4 aA0 = {0,0,0,0}, aA1 = {0,0,0,0};
    float4 aB0 = {0,0,0,0}, aB1 = {0,0,0,0};

    __syncthreads();                    // DMA pass 0 drained

    // ---- pass 0 gathers, pass-1 DMA in flight underneath ----
    STAGE(1, 1)
    const char* tb0 = tl[0] + l * 16;
    GATHER10(tb0, aA0, aA1, LA0, LA1, LAh)      // batch A; A-regs die here
    // A's pass-1 leaves: latency hides under B's gathers
    LA0 = *(const int4*)(lvA + 12);     // trees 12..15 -> pass rows 2..5
    LA1 = *(const int4*)(lvA + 16);     // trees 16..19 -> rows 6..9
    LAh = *(const int2*)(lvA + 10);     // trees 10,11  -> rows 0,1
    GATHER10(tb0, aB0, aB1, LB0, LB1, LBh)      // batch B; B-regs die here
    LB0 = *(const int4*)(lvB + 12);
    LB1 = *(const int4*)(lvB + 16);
    LBh = *(const int2*)(lvB + 10);

    __syncthreads();                    // DMA pass 1 drained

    // ---- pass 1 gathers (tree order within pass: 10,11 at rows 0,1) ----
    const char* tb1 = tl[1] + l * 16;
    {
        uint4 v0 = RD(tb1, 0, LAh.x), v1 = RD(tb1, 1, LAh.y);
        UNACC(aA0, aA1, v0) UNACC(aA0, aA1, v1)
        v0 = RD(tb1, 2, LA0.x); v1 = RD(tb1, 3, LA0.y);
        uint4 v2 = RD(tb1, 4, LA0.z), v3 = RD(tb1, 5, LA0.w);
        UNACC(aA0, aA1, v0) UNACC(aA0, aA1, v1) UNACC(aA0, aA1, v2) UNACC(aA0, aA1, v3)
        v0 = RD(tb1, 6, LA1.x); v1 = RD(tb1, 7, LA1.y);
        v2 = RD(tb1, 8, LA1.z); v3 = RD(tb1, 9, LA1.w);
        UNACC(aA0, aA1, v0) UNACC(aA0, aA1, v1) UNACC(aA0, aA1, v2) UNACC(aA0, aA1, v3)

        v0 = RD(tb1, 0, LBh.x); v1 = RD(tb1, 1, LBh.y);
        UNACC(aB0, aB1, v0) UNACC(aB0, aB1, v1)
        v0 = RD(tb1, 2, LB0.x); v1 = RD(tb1, 3, LB0.y);
        v2 = RD(tb1, 4, LB0.z); v3 = RD(tb1, 5, LB0.w);
        UNACC(aB0, aB1, v0) UNACC(aB0, aB1, v1) UNACC(aB0, aB1, v2) UNACC(aB0, aB1, v3)
        v0 = RD(tb1, 6, LB1.x); v1 = RD(tb1, 7, LB1.y);
        v2 = RD(tb1, 8, LB1.z); v3 = RD(tb1, 9, LB1.w);
        UNACC(aB0, aB1, v0) UNACC(aB0, aB1, v1) UNACC(aB0, aB1, v2) UNACC(aB0, aB1, v3)
    }

#undef STAGE
#undef RD
#undef UNACC
#undef GATHER10

    // each group's 4 lanes write 2 float4 per batch -> contiguous 128B/(b,s)
    float* oA = out + (size_t)bA * OUTW + s * EMB + l * 8;
    float* oB = out + (size_t)bB * OUTW + s * EMB + l * 8;
    *(float4*)(oA)     = aA0;
    *(float4*)(oA + 4) = aA1;
    *(float4*)(oB)     = aB0;
    *(float4*)(oB + 4) = aB1;
}

extern "C" void kernel_launch(void* const* d_in, const int* in_sizes, int n_in,
                              void* d_out, int out_size, void* d_ws, size_t ws_size,
                              hipStream_t stream) {
    const int* leaves  = (const int*)d_in[0];
    const float* embed = (const float*)d_in[1];
    float* out         = (float*)d_out;

    // d_ws: 8.2 MB bf16 table (fully rewritten every call -> deterministic).
    cvt_tab<<<dim3(TAB_F4 / 1024), dim3(256), 0, stream>>>(
        (const float4*)embed, (uint2*)d_ws);

    leaf2emb_v13<<<dim3(NBLK), dim3(THREADS), 0, stream>>>(
        leaves, (const char*)d_ws, out);
}

// Round 14
// 39.663 us; speedup vs baseline: 3.3534x; 3.3534x over previous
//
#include <hip/hip_runtime.h>

// Problem constants
#define NSPLIT  100
#define MTREE   20
#define MAXLEAF 64
#define EMB     32
#define NTREES  2000
#define BATCH   4096
#define OUTW    (NSPLIT*EMB)             // 3200
#define TAB_F4  (NSPLIT*MTREE*MAXLEAF*8) // 1,024,000 float4 in f32 table
#define SPLIT_B 81920                    // bf16 table bytes per split

#define THREADS 1024
#define CHUNKS  8                        // batch-chunks per split
#define BPC     (BATCH/CHUNKS)           // 512 batches/block, 2 per group
#define NBLK    (NSPLIT*CHUNKS)          // 800

// v14 = v13's low-staging geometry with the register pressure designed out.
//  - Whole 80 KiB bf16 split table staged to static LDS up front (5 DMA/lane),
//    ONE barrier, zero further sync. Staging = 800 x 80 KB = 65 MB (the
//    proven wall-time correlate: 262 MB->40us, 524 MB->50us).
//  - STRICTLY sequential batches per thread: A {20 leaves, 20 gathers, write,
//    regs die} then B. Peak live ~56 < the 64 cap of __launch_bounds__
//    (1024,2) (v7-proven tier). v13 spilled (327 MB scratch) because both
//    batches' leaves+accs were live at once (~80 regs).
//  - B's leaf-load latency exposed once/block, hidden by 31 co-resident waves
//    (80 KiB LDS x 2 blocks/CU = 160 KiB exact).
__device__ __forceinline__ unsigned int pk_bf16(float a, float b) {
    unsigned int r;
    asm("v_cvt_pk_bf16_f32 %0, %1, %2" : "=v"(r) : "v"(a), "v"(b));
    return r;
}

__device__ __forceinline__ void stage_dma(const void* gsrc, void* lbase) {
    __builtin_amdgcn_global_load_lds(
        (const __attribute__((address_space(1))) void*)gsrc,
        (__attribute__((address_space(3))) void*)lbase, 16, 0, 0);
}

// ---- kernel 1: f32 table -> bf16 table in d_ws (row-major preserved) ----
__global__ __launch_bounds__(256) void cvt_tab(
    const float4* __restrict__ src, uint2* __restrict__ dst)
{
    const int i0 = blockIdx.x * 1024 + threadIdx.x;
#pragma unroll
    for (int k = 0; k < 4; ++k) {
        const int i = i0 + k * 256;          // 1000 blocks x 1024 = exact
        const float4 v = src[i];
        dst[i] = make_uint2(pk_bf16(v.x, v.y), pk_bf16(v.z, v.w));
    }
}

// ---- kernel 2: whole-table LDS gather, 1 barrier, sequential batches ----
__global__ __launch_bounds__(THREADS, 2) void leaf2emb_v14(
    const int* __restrict__ leaves,     // [BATCH, NTREES]
    const char* __restrict__ tab,       // bf16 table in d_ws, row = 64 B
    float* __restrict__ out)            // [BATCH, OUTW]
{
    __shared__ char tl[SPLIT_B];        // 80 KiB: whole split table

    // XCD-chunked swizzle: 800 = 8 x 100 -> XCD x owns 12.5 consecutive
    // splits; its ~1 MB bf16 slice stays L2-resident for DMA staging.
    const int bid = blockIdx.x;
    const int wkr = (bid & 7) * (NBLK / 8) + (bid >> 3);
    const int s     = wkr >> 3;
    const int chunk = wkr & 7;

    const int tid  = threadIdx.x;
    const int l    = tid & 3;           // lane-in-group: dims [8l, 8l+8)
    const int g    = tid >> 2;          // group id (256 groups, 2 batches each)
    const int w    = tid >> 6;          // wave id (uniform)
    const int lane = tid & 63;

    const char* gtab = tab + (size_t)s * SPLIT_B;

    // ---- stage whole table: 16 waves x 1 KB x 5 rounds = 80 KB exact ----
    {
        const char* gs = gtab + w * 1024 + lane * 16;
        char* lb = tl + w * 1024;
#pragma unroll
        for (int k = 0; k < 5; ++k)
            stage_dma(gs + k * 16384, lb + k * 16384);
    }

    const int bA = chunk * BPC + g;
    const int bB = bA + 256;
    const int4* lvA = (const int4*)(leaves + (size_t)bA * NTREES + s * MTREE);
    const int4* lvB = (const int4*)(leaves + (size_t)bB * NTREES + s * MTREE);

    // batch-A leaves in flight during DMA drain
    int4 L0 = lvA[0], L1 = lvA[1], L2 = lvA[2], L3 = lvA[3], L4 = lvA[4];

    __syncthreads();                    // the kernel's ONLY barrier

    const char* tb  = tl + l * 16;
    const char* tbH = tb + 16 * 4096;   // trees 16..19 (keeps ds offs <64K)

    float4 a0 = {0,0,0,0}, a1 = {0,0,0,0};   // dims [8l..8l+4), [8l+4..8l+8)

#define RD(TB, T, LEAF) (*(const uint4*)((TB) + (T)*4096 + ((LEAF) << 6)))
#define UNACC(V) { \
    a0.x += __uint_as_float((V).x << 16); a0.y += __uint_as_float((V).x & 0xffff0000u); \
    a0.z += __uint_as_float((V).y << 16); a0.w += __uint_as_float((V).y & 0xffff0000u); \
    a1.x += __uint_as_float((V).z << 16); a1.y += __uint_as_float((V).z & 0xffff0000u); \
    a1.z += __uint_as_float((V).w << 16); a1.w += __uint_as_float((V).w & 0xffff0000u); }
#define QUART(TB, T0, LQ) { \
        uint4 v0 = RD(TB, (T0)+0, (LQ).x), v1 = RD(TB, (T0)+1, (LQ).y), \
              v2 = RD(TB, (T0)+2, (LQ).z), v3 = RD(TB, (T0)+3, (LQ).w); \
        UNACC(v0) UNACC(v1) UNACC(v2) UNACC(v3) }
#define GATHER20() \
        QUART(tb,  0,  L0) QUART(tb,  4,  L1) QUART(tb,  8,  L2) \
        QUART(tb,  12, L3) QUART(tbH, 0,  L4)

    // ---- batch A: gathers -> write -> regs die ----
    GATHER20()
    {
        float* oA = out + (size_t)bA * OUTW + s * EMB + l * 8;
        *(float4*)(oA)     = a0;
        *(float4*)(oA + 4) = a1;
    }

    // ---- batch B ----
    L0 = lvB[0]; L1 = lvB[1]; L2 = lvB[2]; L3 = lvB[3]; L4 = lvB[4];
    a0 = make_float4(0, 0, 0, 0);
    a1 = make_float4(0, 0, 0, 0);
    GATHER20()
    {
        float* oB = out + (size_t)bB * OUTW + s * EMB + l * 8;
        *(float4*)(oB)     = a0;
        *(float4*)(oB + 4) = a1;
    }

#undef RD
#undef UNACC
#undef QUART
#undef GATHER20
}

extern "C" void kernel_launch(void* const* d_in, const int* in_sizes, int n_in,
                              void* d_out, int out_size, void* d_ws, size_t ws_size,
                              hipStream_t stream) {
    const int* leaves  = (const int*)d_in[0];
    const float* embed = (const float*)d_in[1];
    float* out         = (float*)d_out;

    // d_ws: 8.2 MB bf16 table (fully rewritten every call -> deterministic).
    cvt_tab<<<dim3(TAB_F4 / 1024), dim3(256), 0, stream>>>(
        (const float4*)embed, (uint2*)d_ws);

    leaf2emb_v14<<<dim3(NBLK), dim3(THREADS), 0, stream>>>(
        leaves, (const char*)d_ws, out);
}

// Round 15
// 36.042 us; speedup vs baseline: 3.6902x; 1.1005x over previous
//
#include <hip/hip_runtime.h>

// Problem constants
#define NSPLIT  100
#define MTREE   20
#define MAXLEAF 64
#define EMB     32
#define NTREES  2000
#define BATCH   4096
#define OUTW    (NSPLIT*EMB)             // 3200
#define TAB_F4  (NSPLIT*MTREE*MAXLEAF*8) // 1,024,000 float4 in f32 table
#define SPLIT_B 81920                    // bf16 table bytes per split

#define THREADS 1024
#define CHUNKS  8                        // batch-chunks per split
#define BPC     (BATCH/CHUNKS)           // 512 batches/block, 2 per group
#define NBLK    (NSPLIT*CHUNKS)          // 800

// v15: attack the latency wall (v4 vs v14 falsified port/VALU/staging as
// limits; every pipe ~22% busy -> lockstep 4-deep lgkm chains don't overlap).
//  - 128-VGPR tier: __launch_bounds__(1024,1) -> 16 waves/CU, 16 ds_read_b128
//    IN FLIGHT per wave (64 VGPRs of data) before first consume.
//  - XOR bank-swizzle: bf16 64B rows occupy only half the banks (parity
//    classes). Chunk c of row r stored at slot c^((r>>1)&3) -> 8 bank
//    classes. cvt_tab PRE-swizzles d_ws so staging DMA stays linear (the
//    global_load_lds both-sides rule); gather XORs lane<<4 into the offset.
//  - v_dot2_f32_bf16 accumulate: acc += w.lo (sel=1.0bf16|0) in one VOP3P
//    instr -> 8 instr/uint4 vs 16 shift/and/add.
//  - batch-B leaves load under batch-A consumes. Peak live ~106 regs.
__device__ __forceinline__ unsigned int pk_bf16(float a, float b) {
    unsigned int r;
    asm("v_cvt_pk_bf16_f32 %0, %1, %2" : "=v"(r) : "v"(a), "v"(b));
    return r;
}

__device__ __forceinline__ void stage_dma(const void* gsrc, void* lbase) {
    __builtin_amdgcn_global_load_lds(
        (const __attribute__((address_space(1))) void*)gsrc,
        (__attribute__((address_space(3))) void*)lbase, 16, 0, 0);
}

// a += (sel selects lo or hi bf16 half of w, weight 1.0): one VOP3P dot2.
__device__ __forceinline__ void d2(float& a, unsigned int w, unsigned int sel) {
    asm("v_dot2_f32_bf16 %0, %1, %2, %0" : "+v"(a) : "v"(w), "v"(sel));
}

// ---- kernel 1: f32 table -> bf16 table in d_ws, BANK-SWIZZLED layout ----
// Logical 16B chunk c (c=0..3) of row r lands at physical slot c^((r>>1)&3).
__global__ __launch_bounds__(256) void cvt_tab(
    const float4* __restrict__ src, char* __restrict__ dst)
{
    const int i0 = blockIdx.x * 1024 + threadIdx.x;
#pragma unroll
    for (int k = 0; k < 4; ++k) {
        const int i = i0 + k * 256;          // 1000 blocks x 1024 = exact
        const float4 v = src[i];
        const uint2 val = make_uint2(pk_bf16(v.x, v.y), pk_bf16(v.z, v.w));
        const int row = i >> 3;              // 8 float4 per 32-dim row
        const int f   = i & 7;
        const int c   = f >> 1;              // logical 16B chunk
        const int h   = f & 1;               // low/high 8B of chunk
        const int sw  = (row >> 1) & 3;
        *(uint2*)(dst + (size_t)row * 64 + (((c ^ sw) << 4) | (h << 3))) = val;
    }
}

// ---- kernel 2: whole-table LDS gather, 16-deep ILP, dot2 accumulate ----
__global__ __launch_bounds__(THREADS, 1) void leaf2emb_v15(
    const int* __restrict__ leaves,     // [BATCH, NTREES]
    const char* __restrict__ tab,       // SWIZZLED bf16 table in d_ws
    float* __restrict__ out)            // [BATCH, OUTW]
{
    __shared__ char tl[SPLIT_B];        // 80 KiB: whole split table

    // XCD-chunked swizzle: 800 = 8 x 100.
    const int bid = blockIdx.x;
    const int wkr = (bid & 7) * (NBLK / 8) + (bid >> 3);
    const int s     = wkr >> 3;
    const int chunk = wkr & 7;

    const int tid  = threadIdx.x;
    const int l    = tid & 3;           // lane-in-group: dims [8l, 8l+8)
    const int g    = tid >> 2;          // group id (256 groups, 2 batches each)
    const int w    = tid >> 6;          // wave id
    const int lane = tid & 63;
    const int lx4  = l << 4;

    const char* gtab = tab + (size_t)s * SPLIT_B;

    // stage whole (pre-swizzled) table linearly: 16 waves x 1KB x 5 = 80 KB
    {
        const char* gs = gtab + w * 1024 + lane * 16;
        char* lb = tl + w * 1024;
#pragma unroll
        for (int k = 0; k < 5; ++k)
            stage_dma(gs + k * 16384, lb + k * 16384);
    }

    const int bA = chunk * BPC + g;
    const int bB = bA + 256;
    const int4* lvA = (const int4*)(leaves + (size_t)bA * NTREES + s * MTREE);
    const int4* lvB = (const int4*)(leaves + (size_t)bB * NTREES + s * MTREE);

    int4 L0 = lvA[0], L1 = lvA[1], L2 = lvA[2], L3 = lvA[3], L4 = lvA[4];

    __syncthreads();                    // the kernel's ONLY barrier

    const char* tb = tl;
    const unsigned int selL = 0x00003F80u;   // {hi=0, lo=1.0bf16}
    const unsigned int selH = 0x3F800000u;   // {hi=1.0bf16, lo=0}

    // swizzled within-tree offset: row LEAF, this lane's logical chunk l
#define SWZ(LEAF) (((LEAF) << 6) + (((((LEAF) >> 1) & 3) << 4) ^ lx4))
#define ROWL(T, LEAF) (*(const uint4*)(tb + (T) * 4096 + SWZ(LEAF)))
#define ROWH(T, LEAF) (*(const uint4*)(tb + ((T) - 16) * 4096 + (SWZ(LEAF) | 0x10000)))
#define D2ACC(V) { \
        d2(a0.x, (V).x, selL); d2(a0.y, (V).x, selH); \
        d2(a0.z, (V).y, selL); d2(a0.w, (V).y, selH); \
        d2(a1.x, (V).z, selL); d2(a1.y, (V).z, selH); \
        d2(a1.z, (V).w, selL); d2(a1.w, (V).w, selH); }

    float4 a0 = {0,0,0,0}, a1 = {0,0,0,0};

    // ---- batch A: 16 reads in flight, then last 4; B-leaves under consume --
    uint4 v00 = ROWL(0,  L0.x), v01 = ROWL(1,  L0.y), v02 = ROWL(2,  L0.z), v03 = ROWL(3,  L0.w);
    uint4 v04 = ROWL(4,  L1.x), v05 = ROWL(5,  L1.y), v06 = ROWL(6,  L1.z), v07 = ROWL(7,  L1.w);
    uint4 v08 = ROWL(8,  L2.x), v09 = ROWL(9,  L2.y), v10 = ROWL(10, L2.z), v11 = ROWL(11, L2.w);
    uint4 v12 = ROWL(12, L3.x), v13 = ROWL(13, L3.y), v14 = ROWL(14, L3.z), v15 = ROWL(15, L3.w);
    uint4 v16 = ROWH(16, L4.x), v17 = ROWH(17, L4.y), v18 = ROWH(18, L4.z), v19 = ROWH(19, L4.w);
    // batch-B leaves: global latency hides under the 160 dot2s below
    int4 M0 = lvB[0], M1 = lvB[1], M2 = lvB[2], M3 = lvB[3], M4 = lvB[4];
    D2ACC(v00) D2ACC(v01) D2ACC(v02) D2ACC(v03)
    D2ACC(v04) D2ACC(v05) D2ACC(v06) D2ACC(v07)
    D2ACC(v08) D2ACC(v09) D2ACC(v10) D2ACC(v11)
    D2ACC(v12) D2ACC(v13) D2ACC(v14) D2ACC(v15)
    D2ACC(v16) D2ACC(v17) D2ACC(v18) D2ACC(v19)
    {
        float* oA = out + (size_t)bA * OUTW + s * EMB + l * 8;
        *(float4*)(oA)     = a0;
        *(float4*)(oA + 4) = a1;
    }

    // ---- batch B ----
    a0 = make_float4(0, 0, 0, 0);
    a1 = make_float4(0, 0, 0, 0);
    v00 = ROWL(0,  M0.x); v01 = ROWL(1,  M0.y); v02 = ROWL(2,  M0.z); v03 = ROWL(3,  M0.w);
    v04 = ROWL(4,  M1.x); v05 = ROWL(5,  M1.y); v06 = ROWL(6,  M1.z); v07 = ROWL(7,  M1.w);
    v08 = ROWL(8,  M2.x); v09 = ROWL(9,  M2.y); v10 = ROWL(10, M2.z); v11 = ROWL(11, M2.w);
    v12 = ROWL(12, M3.x); v13 = ROWL(13, M3.y); v14 = ROWL(14, M3.z); v15 = ROWL(15, M3.w);
    v16 = ROWH(16, M4.x); v17 = ROWH(17, M4.y); v18 = ROWH(18, M4.z); v19 = ROWH(19, M4.w);
    D2ACC(v00) D2ACC(v01) D2ACC(v02) D2ACC(v03)
    D2ACC(v04) D2ACC(v05) D2ACC(v06) D2ACC(v07)
    D2ACC(v08) D2ACC(v09) D2ACC(v10) D2ACC(v11)
    D2ACC(v12) D2ACC(v13) D2ACC(v14) D2ACC(v15)
    D2ACC(v16) D2ACC(v17) D2ACC(v18) D2ACC(v19)
    {
        float* oB = out + (size_t)bB * OUTW + s * EMB + l * 8;
        *(float4*)(oB)     = a0;
        *(float4*)(oB + 4) = a1;
    }

#undef SWZ
#undef ROWL
#undef ROWH
#undef D2ACC
}

extern "C" void kernel_launch(void* const* d_in, const int* in_sizes, int n_in,
                              void* d_out, int out_size, void* d_ws, size_t ws_size,
                              hipStream_t stream) {
    const int* leaves  = (const int*)d_in[0];
    const float* embed = (const float*)d_in[1];
    float* out         = (float*)d_out;

    // d_ws: 8.2 MB swizzled bf16 table (fully rewritten every call).
    cvt_tab<<<dim3(TAB_F4 / 1024), dim3(256), 0, stream>>>(
        (const float4*)embed, (char*)d_ws);

    leaf2emb_v15<<<dim3(NBLK), dim3(THREADS), 0, stream>>>(
        leaves, (const char*)d_ws, out);
}